// Round 12
// baseline (4601.871 us; speedup 1.0000x reference)
//
#include <hip/hip_runtime.h>
#include <hip/hip_bf16.h>

typedef __bf16 bf16x8 __attribute__((ext_vector_type(8)));
typedef __bf16 bf16x4 __attribute__((ext_vector_type(4)));
typedef float  f32x4  __attribute__((ext_vector_type(4)));

#define S_LEN  256
#define BATCH  16
#define EDIM   512
#define HDIM   512
#define VOCAB  32000
#define G4     2048          // 4*H
#define M_ROWS 4096          // S*B
#define NWG_LSTM 32
#define NTILE_N  (VOCAB / 128)   // 250 logit n-tiles
#define NTILE_M  (M_ROWS / 128)  // 32 logit m-tiles

// fused-launch block partition (order = dependency order; in-order dispatch)
#define NB_PROD  NWG_LSTM
#define NB_WCAST 2048
#define MIX_PER  (NTILE_N + 128)      // 250 logit tiles + 128 finish rows per mt
#define NB_MIX   (NTILE_M * MIX_PER)  // 12096
#define B_WC0    NB_PROD
#define B_MIX0   (B_WC0 + NB_WCAST)
#define NB_ALL   (B_MIX0 + NB_MIX)    // 14176

// ------- ws layout (bytes) -------
// COUNTER RULE: all counters/accumulators are L3-scope (AGENT atomics or
// sc0sc1 ops) -> the in-graph memset resets them every replay (R9 lesson:
// no-scope atomics leave dirty L2 lines memset can't reach).
#define OFF_CNT4  0                         // int x4 @ 0,256,512,768: arrival lines
#define OFF_MIR   1024                      // int: published completed-step count
#define OFF_WCNT  1280                      // int: wcast blocks done
#define OFF_CROW  1536                      // int[32]: logit tiles done per row-block
#define OFF_RSUM  4096                      // float[4096]: per-row sum of exp(logit)
#define OFF_WLIN  32768                     // bf16[32000*512]
#define OFF_HS    (OFF_WLIN + 32768000)     // bf16[257*16*512]; slab 0 zeroed (h_0)
// total = 37,011,456 bytes

// ---- device-coherent (write-through to Infinity Cache, L3-scope) ops ----
__device__ __forceinline__ void store_short_sc(__bf16* p, __bf16 v) {
  unsigned short u = __builtin_bit_cast(unsigned short, v);
  asm volatile("global_store_short %0, %1, off sc0 sc1" :: "v"(p), "v"(u) : "memory");
}
__device__ __forceinline__ void store_f32_sc(float* p, float v) {
  asm volatile("global_store_dword %0, %1, off sc0 sc1" :: "v"(p), "v"(v) : "memory");
}
__device__ __forceinline__ void store_b16x4_sc(__bf16* p, bf16x4 v) {
  asm volatile("global_store_dwordx2 %0, %1, off sc0 sc1" :: "v"(p), "v"(v) : "memory");
}
__device__ __forceinline__ void store_int_sc(int* p, int v) {
  asm volatile("global_store_dword %0, %1, off sc0 sc1" :: "v"(p), "v"(v) : "memory");
}
__device__ __forceinline__ int load_cnt_sc(const int* p) {   // L3-coherent read
  int r;
  asm volatile("global_load_dword %0, %1, off sc0 sc1\n\ts_waitcnt vmcnt(0)"
               : "=v"(r) : "v"(p) : "memory");
  return r;
}
__device__ __forceinline__ float load_f32_sc(const float* p) {
  float r;
  asm volatile("global_load_dword %0, %1, off sc0 sc1\n\ts_waitcnt vmcnt(0)"
               : "=v"(r) : "v"(p) : "memory");
  return r;
}

#define GLOAD_LDS(gsrc, ldst)                                                  \
  __builtin_amdgcn_global_load_lds(                                            \
      (const __attribute__((address_space(1))) void*)(gsrc),                   \
      (__attribute__((address_space(3))) void*)(ldst), 16, 0, 0)

__device__ __forceinline__ bf16x8 cvt8(float4 a, float4 b) {
  bf16x8 t = { (__bf16)a.x, (__bf16)a.y, (__bf16)a.z, (__bf16)a.w,
               (__bf16)b.x, (__bf16)b.y, (__bf16)b.z, (__bf16)b.w };
  return t;
}

// ---------------- ONE fused launch: everything ----------------
// [0,32): self-contained persistent LSTM producers (embed gather + x-proj
//   MFMA in barrier shadow + h-recurrence MFMA). No prep dependency.
// [32,2080): W_lin f32->bf16 cast (sc1) + wcnt counter.
// [2080,14176): per-mt: 250 logit tiles (poll wcnt & mir; GEMM; sc1 out;
//   per-row sumexp atomicAdd into rsum; cnt_row[mt]++) then 128 finish
//   rows (poll cnt_row[mt]==250; out -= log(rsum[row]), plain stores).
// Deadlock-free: every poller's unlockers are strictly earlier in dispatch
// order; no block waits on later siblings.
__global__ __launch_bounds__(256, 2) void k_fused(
    const int* __restrict__ tok, const float* __restrict__ embed,
    const float* __restrict__ W_ih, const float* __restrict__ Whh,
    const float* __restrict__ b_ih, const float* __restrict__ b_hh,
    const float* __restrict__ W_lin, __bf16* __restrict__ wlinb,
    __bf16* __restrict__ hs_full, int* __restrict__ cnt4, int* __restrict__ mir,
    int* __restrict__ wcnt, int* __restrict__ cnt_row, float* __restrict__ rsum,
    float* __restrict__ out, const float* __restrict__ b_lin) {
  const int tid = threadIdx.x;
  const int bid = blockIdx.x;

  if (bid >= B_MIX0) {
    __shared__ __align__(16) __bf16 As[128 * 64];
    __shared__ __align__(16) __bf16 Bs[128 * 64];
    const int t  = bid - B_MIX0;
    const int mt = t / MIX_PER, r = t % MIX_PER;
    if (r < NTILE_N) {
      // ---------------- logit tile + in-register sumexp ----------------
      const int m0 = mt * 128, n0 = r * 128;
      if (tid == 0) {
        while (load_cnt_sc(wcnt) < NB_WCAST) __builtin_amdgcn_s_sleep(16);
        const int need = 8 * (mt + 1);
        int cur;
        while ((cur = load_cnt_sc(mir)) < need) {
          if (need - cur > 32) __builtin_amdgcn_s_sleep(64);
          else                 __builtin_amdgcn_s_sleep(8);
        }
      }
      __syncthreads();
      const __bf16* A = hs_full + BATCH * HDIM;   // hs rows m = s*16+b
      const int wave = tid >> 6, lane = tid & 63;
      const int wm = (wave >> 1) * 64, wn = (wave & 1) * 64;
      const int lrow = lane & 15;
      const int kbyte = (lane >> 4) * 16;
      f32x4 acc[4][4];
      #pragma unroll
      for (int i = 0; i < 4; ++i)
        #pragma unroll
        for (int j = 0; j < 4; ++j) { acc[i][j][0]=0.f; acc[i][j][1]=0.f; acc[i][j][2]=0.f; acc[i][j][3]=0.f; }
      for (int k0 = 0; k0 < HDIM; k0 += 64) {
        #pragma unroll
        for (int p = 0; p < 4; ++p) {
          int c = p * 256 + tid;
          int row = c >> 3, colE = (c & 7) * 8;
          GLOAD_LDS(A + (size_t)(m0 + row) * HDIM + k0 + colE, (char*)As + c * 16);
          GLOAD_LDS(wlinb + (size_t)(n0 + row) * HDIM + k0 + colE, (char*)Bs + c * 16);
        }
        __syncthreads();
        #pragma unroll
        for (int ks = 0; ks < 2; ++ks) {
          bf16x8 af[4], bfv[4];
          #pragma unroll
          for (int i = 0; i < 4; ++i) {
            af[i]  = *(const bf16x8*)((const char*)As + (wm + i * 16 + lrow) * 128 + ks * 64 + kbyte);
            bfv[i] = *(const bf16x8*)((const char*)Bs + (wn + i * 16 + lrow) * 128 + ks * 64 + kbyte);
          }
          #pragma unroll
          for (int i = 0; i < 4; ++i)
            #pragma unroll
            for (int j = 0; j < 4; ++j)
              acc[i][j] = __builtin_amdgcn_mfma_f32_16x16x32_bf16(af[i], bfv[j], acc[i][j], 0, 0, 0);
        }
        __syncthreads();
      }
      // epilogue: add bias, sc1-store logits, accumulate per-row sumexp
      const int col = lane & 15;
      const int rbase = (lane >> 4) * 4;
      f32x4 rs[4];                                 // per-i row partial sums
      #pragma unroll
      for (int i = 0; i < 4; ++i) { rs[i][0]=0.f; rs[i][1]=0.f; rs[i][2]=0.f; rs[i][3]=0.f; }
      #pragma unroll
      for (int i = 0; i < 4; ++i)
        #pragma unroll
        for (int j = 0; j < 4; ++j) {
          int nn = n0 + wn + j * 16 + col;
          float bv = b_lin[nn];
          #pragma unroll
          for (int rr = 0; rr < 4; ++rr) {
            int mm = m0 + wm + i * 16 + rbase + rr;
            float v = acc[i][j][rr] + bv;
            store_f32_sc(&out[(size_t)mm * VOCAB + nn], v);
            rs[i][rr] += __expf(v);                // |v| <= ~23: no overflow
          }
        }
      // butterfly over the 16 lanes sharing each row group (lane&15)
      #pragma unroll
      for (int off = 8; off > 0; off >>= 1)
        #pragma unroll
        for (int i = 0; i < 4; ++i) {
          rs[i][0] += __shfl_xor(rs[i][0], off);
          rs[i][1] += __shfl_xor(rs[i][1], off);
          rs[i][2] += __shfl_xor(rs[i][2], off);
          rs[i][3] += __shfl_xor(rs[i][3], off);
        }
      if ((lane & 15) == 0) {
        #pragma unroll
        for (int i = 0; i < 4; ++i)
          #pragma unroll
          for (int rr = 0; rr < 4; ++rr)
            __hip_atomic_fetch_add(rsum + m0 + wm + i * 16 + rbase + rr,
                                   rs[i][rr], __ATOMIC_RELAXED, __HIP_MEMORY_SCOPE_AGENT);
      }
      __syncthreads();                             // drain sc1 stores + atomics
      if (tid == 0)
        __hip_atomic_fetch_add(cnt_row + mt, 1, __ATOMIC_RELAXED, __HIP_MEMORY_SCOPE_AGENT);
      return;
    }
    // ---------------- finish row: out -= log(rsum[row]) ----------------
    const int row = mt * 128 + (r - NTILE_N);
    __shared__ float lse_s;
    if (tid == 0) {
      while (load_cnt_sc(cnt_row + mt) < NTILE_N) __builtin_amdgcn_s_sleep(32);
      lse_s = __logf(load_f32_sc(rsum + row));
    }
    __syncthreads();
    const float lse = lse_s;
    float* p = out + (size_t)row * VOCAB;
    for (int i = tid; i < VOCAB / 4; i += 256) {
      float4 v = ((const float4*)p)[i];            // first-touch (deterministic data)
      v.x -= lse; v.y -= lse; v.z -= lse; v.w -= lse;
      ((float4*)p)[i] = v;                         // final: plain store
    }
    return;
  }

  if (bid >= B_WC0) {
    // ---------------- W_lin f32 -> bf16 cast (sc1 for cross-XCD readers) ----------------
    for (int i = (bid - B_WC0) * 256 + tid; i < VOCAB * HDIM / 4; i += NB_WCAST * 256) {
      float4 v = ((const float4*)W_lin)[i];
      bf16x4 o = { (__bf16)v.x, (__bf16)v.y, (__bf16)v.z, (__bf16)v.w };
      store_b16x4_sc(wlinb + (size_t)i * 4, o);
    }
    __syncthreads();                               // drain sc1 stores (vmcnt 0)
    if (tid == 0)
      __hip_atomic_fetch_add(wcnt, 1, __ATOMIC_RELAXED, __HIP_MEMORY_SCOPE_AGENT);
    return;
  }

  // ---------------- producer: self-contained persistent LSTM ----------------
  __builtin_amdgcn_s_setprio(1);
  const int lane = tid & 63;
  const int wv   = tid >> 6;               // 0..3
  const int W    = bid * 4 + wv;           // 0..127
  const int c0   = W * 4;                  // first cell owned by this wave
  const int nl   = lane & 15;              // MFMA col (n_local) / A row (batch)
  const int g    = nl >> 2, cl = nl & 3;
  const int Grow = g * 512 + c0 + cl;      // gate row in [0,2048)
  const int kb   = (lane >> 4) * 8;        // per-lane K offset
  const int B0   = (lane >> 4) * 4;        // batch base of acc regs

  // ---- B-frags: W_hh AND W_ih rows (fp32 -> bf16), 128 VGPRs, loaded once ----
  bf16x8 hfrag[16], ifrag[16];
  #pragma unroll
  for (int kk = 0; kk < 16; ++kk) {
    const float4* sh = (const float4*)(Whh + (size_t)Grow * 512 + kk * 32 + kb);
    hfrag[kk] = cvt8(sh[0], sh[1]);
    const float4* si = (const float4*)(W_ih + (size_t)Grow * 512 + kk * 32 + kb);
    ifrag[kk] = cvt8(si[0], si[1]);
  }
  const float bsum = b_ih[Grow] + b_hh[Grow];

  // x-projection for step s: all-lane MFMA work done in the barrier shadow
  f32x4 xa0, xa1;
  auto xacc = [&](int sidx) {
    int tokv = tok[sidx * BATCH + nl];
    const float* er = embed + (size_t)tokv * EDIM + kb;
    xa0[0] = bsum; xa0[1] = bsum; xa0[2] = bsum; xa0[3] = bsum;
    xa1[0] = 0.f;  xa1[1] = 0.f;  xa1[2] = 0.f;  xa1[3] = 0.f;
    #pragma unroll
    for (int kk = 0; kk < 16; kk += 2) {
      const float4* e0 = (const float4*)(er + kk * 32);
      xa0 = __builtin_amdgcn_mfma_f32_16x16x32_bf16(cvt8(e0[0], e0[1]), ifrag[kk], xa0, 0, 0, 0);
      const float4* e1 = (const float4*)(er + (kk + 1) * 32);
      xa1 = __builtin_amdgcn_mfma_f32_16x16x32_bf16(cvt8(e1[0], e1[1]), ifrag[kk + 1], xa1, 0, 0, 0);
    }
  };
  xacc(0);

  float c_reg[4] = {0.f, 0.f, 0.f, 0.f};
  const int lbase = (lane & 48) | (lane & 3);
  int* myline = cnt4 + (bid & 3) * 64;     // 4 x 256B arrival lines

  for (int s = 0; s < S_LEN; ++s) {
    // A-frags: h_s[batch=nl][k] (first-touch; L3-resident slab)
    const __bf16* hrow = hs_full + (size_t)s * 8192 + nl * 512 + kb;
    bf16x8 afrag[16];
    #pragma unroll
    for (int kk = 0; kk < 16; ++kk)
      afrag[kk] = *(const bf16x8*)(hrow + kk * 32);

    f32x4 acc0 = xa0, acc1 = xa1;          // C-in = x-proj + biases
    #pragma unroll
    for (int kk = 0; kk < 16; kk += 2) {
      acc0 = __builtin_amdgcn_mfma_f32_16x16x32_bf16(afrag[kk],     hfrag[kk],     acc0, 0, 0, 0);
      acc1 = __builtin_amdgcn_mfma_f32_16x16x32_bf16(afrag[kk + 1], hfrag[kk + 1], acc1, 0, 0, 0);
    }

    f32x4 gates;
    #pragma unroll
    for (int r = 0; r < 4; ++r) gates[r] = acc0[r] + acc1[r];

    // redistribute: this lane takes i,f,g,o of cell c0+(lane&3), batches B0..B0+3
    __bf16* dstbase = hs_full + (size_t)(s + 1) * 8192 + (size_t)B0 * 512 + c0 + (lane & 3);
    #pragma unroll
    for (int r = 0; r < 4; ++r) {
      float ig = __shfl(gates[r], lbase + 0);
      float fg = __shfl(gates[r], lbase + 4);
      float gg = __shfl(gates[r], lbase + 8);
      float og = __shfl(gates[r], lbase + 12);
      float si = 1.f / (1.f + __expf(-ig));
      float sf = 1.f / (1.f + __expf(-fg));
      float so = 1.f / (1.f + __expf(-og));
      float ag = fabsf(gg), eg = __expf(-2.f * ag);
      float tg = __builtin_copysignf((1.f - eg) / (1.f + eg), gg);
      float c  = sf * c_reg[r] + si * tg;
      c_reg[r] = c;
      float ac = fabsf(c), ec = __expf(-2.f * ac);
      float tc = __builtin_copysignf((1.f - ec) / (1.f + ec), c);
      float h  = so * tc;
      if ((lane & 12) == 0)
        store_short_sc(dstbase + (size_t)r * 512, (__bf16)h);
    }

    __syncthreads();                       // all 4 waves drain sc1 h stores
    if (tid == 0)                          // arrival ASAP (4-way split lines)
      __hip_atomic_fetch_add(myline, 1, __ATOMIC_RELAXED, __HIP_MEMORY_SCOPE_AGENT);

    if (s + 1 < S_LEN) xacc(s + 1);        // x-proj for next step in the shadow

    if (tid == 0) {
      const int target = NWG_LSTM * (s + 1);
      while (load_cnt_sc(cnt4) + load_cnt_sc(cnt4 + 64) +
             load_cnt_sc(cnt4 + 128) + load_cnt_sc(cnt4 + 192) < target) {}
      if (bid == 0) store_int_sc(mir, s + 1);
    }
    __syncthreads();
  }
}

extern "C" void kernel_launch(void* const* d_in, const int* in_sizes, int n_in,
                              void* d_out, int out_size, void* d_ws, size_t ws_size,
                              hipStream_t stream) {
  const int*   tok   = (const int*)d_in[0];
  // d_in[1] = input_lengths: unused by the reference
  const float* embed = (const float*)d_in[2];
  const float* W_ih  = (const float*)d_in[3];
  const float* W_hh  = (const float*)d_in[4];
  const float* b_ih  = (const float*)d_in[5];
  const float* b_hh  = (const float*)d_in[6];
  const float* W_lin = (const float*)d_in[7];
  const float* b_lin = (const float*)d_in[8];
  float* out = (float*)d_out;
  char*  ws  = (char*)d_ws;

  int*    cnt4     = (int*)(ws + OFF_CNT4);
  int*    mir      = (int*)(ws + OFF_MIR);
  int*    wcnt     = (int*)(ws + OFF_WCNT);
  int*    cnt_row  = (int*)(ws + OFF_CROW);
  float*  rsum     = (float*)(ws + OFF_RSUM);
  __bf16* wlinb    = (__bf16*)(ws + OFF_WLIN);
  __bf16* hs_full  = (__bf16*)(ws + OFF_HS);

  // zero all counters + rsum + h_0 slab (small; required every replay)
  hipMemsetAsync(ws, 0, OFF_RSUM + M_ROWS * sizeof(float), stream);
  hipMemsetAsync(ws + OFF_HS, 0, BATCH * HDIM * sizeof(__bf16), stream);

  k_fused<<<NB_ALL, 256, 0, stream>>>(tok, embed, W_ih, W_hh, b_ih, b_hh,
                                      W_lin, wlinb, hs_full, cnt4, mir,
                                      wcnt, cnt_row, rsum, out, b_lin);
}

// Round 13
// 2921.715 us; speedup vs baseline: 1.5751x; 1.5751x over previous
//
#include <hip/hip_runtime.h>
#include <hip/hip_bf16.h>

typedef __bf16 bf16x8 __attribute__((ext_vector_type(8)));
typedef __bf16 bf16x4 __attribute__((ext_vector_type(4)));
typedef float  f32x4  __attribute__((ext_vector_type(4)));

#define S_LEN  256
#define BATCH  16
#define EDIM   512
#define HDIM   512
#define VOCAB  32000
#define G4     2048          // 4*H
#define M_ROWS 4096          // S*B
#define NWG_LSTM 32
#define NTILE_N  (VOCAB / 128)   // 250 logit n-tiles
#define NTILE_M  (M_ROWS / 128)  // 32 logit m-tiles

// fused-launch block partition (order = dependency order; in-order dispatch)
#define NB_PROD NWG_LSTM
#define NB_XP   512                  // 32 rb x 16 nt
#define NB_LOG  (NTILE_M * NTILE_N)  // 8000 logit tiles
#define NB_FIN  512                  // 512 finish blocks x 8 rows
#define B_XP0   NB_PROD
#define B_LOG0  (B_XP0 + NB_XP)
#define B_FIN0  (B_LOG0 + NB_LOG)
#define NB_ALL  (B_FIN0 + NB_FIN)    // 9056

// ------- ws layout (bytes) -------
// COUNTER RULE: all counters/accumulators are L3-scope (AGENT atomics or
// sc0sc1 ops) so the in-graph memset resets them every replay (R9 lesson:
// no-scope atomics leave dirty L2 lines memset can't reach).
#define OFF_CNT   0                         // int: LSTM step barrier counter
#define OFF_MIR   256                       // int: published completed-step count
#define OFF_XPROW 512                       // int[32]: xp tiles done per row-block
#define OFF_CROW  1024                      // int[32]: logit tiles done per row-block
#define OFF_RSUM  4096                      // float[4096]: per-row sum of exp(logit)
#define OFF_BIAS  20480                     // float[2048] = b_ih + b_hh
#define OFF_X     28672                     // bf16[4096*512] gathered embeddings
#define OFF_WIH   (OFF_X + 4194304)         // bf16[2048*512]
#define OFF_WLIN  (OFF_WIH + 2097152)       // bf16[32000*512]
#define OFF_XP    (OFF_WLIN + 32768000)     // float[4096*2048]
#define OFF_HS    (OFF_XP + 33554432)       // bf16[257*16*512]; slab 0 zeroed (h_0)
// total = 76,853,248 bytes

// ---- device-coherent (write-through to Infinity Cache, L3-scope) ops ----
__device__ __forceinline__ void store_short_sc(__bf16* p, __bf16 v) {
  unsigned short u = __builtin_bit_cast(unsigned short, v);
  asm volatile("global_store_short %0, %1, off sc0 sc1" :: "v"(p), "v"(u) : "memory");
}
__device__ __forceinline__ void store_f32_sc(float* p, float v) {
  asm volatile("global_store_dword %0, %1, off sc0 sc1" :: "v"(p), "v"(v) : "memory");
}
__device__ __forceinline__ void store_int_sc(int* p, int v) {
  asm volatile("global_store_dword %0, %1, off sc0 sc1" :: "v"(p), "v"(v) : "memory");
}
__device__ __forceinline__ int load_cnt_sc(const int* p) {   // L3-coherent read
  int r;
  asm volatile("global_load_dword %0, %1, off sc0 sc1\n\ts_waitcnt vmcnt(0)"
               : "=v"(r) : "v"(p) : "memory");
  return r;
}
__device__ __forceinline__ float load_f32_sc(const float* p) {
  float r;
  asm volatile("global_load_dword %0, %1, off sc0 sc1\n\ts_waitcnt vmcnt(0)"
               : "=v"(r) : "v"(p) : "memory");
  return r;
}

#define GLOAD_LDS(gsrc, ldst)                                                  \
  __builtin_amdgcn_global_load_lds(                                            \
      (const __attribute__((address_space(1))) void*)(gsrc),                   \
      (__attribute__((address_space(3))) void*)(ldst), 16, 0, 0)

// ---------------- merged prep kernel (separate launch; kernel-boundary
// coherence covers the handoff to k_fused) ----------------
__global__ __launch_bounds__(256) void k_prep(
    const int* __restrict__ tok, const float* __restrict__ embed, __bf16* __restrict__ xb,
    const float* __restrict__ W_ih, __bf16* __restrict__ wihb,
    const float* __restrict__ W_lin, __bf16* __restrict__ wlinb,
    const float* __restrict__ b_ih, const float* __restrict__ b_hh, float* __restrict__ bb) {
  const int b = blockIdx.x, tid = threadIdx.x;
  if (b < 2048) {                       // embedding gather+cast: 4096*128 float4 chunks
    int i = b * 256 + tid;
    int m = i >> 7, c = i & 127;
    int t = tok[m];
    float4 v = ((const float4*)(embed + (size_t)t * EDIM))[c];
    bf16x4 o = { (__bf16)v.x, (__bf16)v.y, (__bf16)v.z, (__bf16)v.w };
    ((bf16x4*)(xb + (size_t)m * EDIM))[c] = o;
  } else if (b < 3072) {                // W_ih cast: 262144 float4
    int i = (b - 2048) * 256 + tid;
    float4 v = ((const float4*)W_ih)[i];
    bf16x4 o = { (__bf16)v.x, (__bf16)v.y, (__bf16)v.z, (__bf16)v.w };
    ((bf16x4*)wihb)[i] = o;
  } else if (b < 5120) {                // W_lin cast: 4,096,000 float4, grid-stride
    for (int i = (b - 3072) * 256 + tid; i < VOCAB * HDIM / 4; i += 2048 * 256) {
      float4 v = ((const float4*)W_lin)[i];
      bf16x4 o = { (__bf16)v.x, (__bf16)v.y, (__bf16)v.z, (__bf16)v.w };
      ((bf16x4*)wlinb)[i] = o;
    }
  } else {                              // bias sum
    int i = (b - 5120) * 256 + tid;
    if (i < G4) bb[i] = b_ih[i] + b_hh[i];
  }
}

// ------- shared 128x128 MFMA GEMM tile body: D = A[M,K]*B[N,K]^T + bias -------
// sc1 stores: results land in coherent L3 for same-launch cross-XCD readers.
__device__ __forceinline__ void gemm_tile_body(
    const __bf16* __restrict__ A, const __bf16* __restrict__ B,
    float* __restrict__ D, const float* __restrict__ bias,
    int N, int K, int m0, int n0, __bf16* As, __bf16* Bs) {
  const int tid  = threadIdx.x;
  const int wave = tid >> 6, lane = tid & 63;
  const int wm   = (wave >> 1) * 64, wn = (wave & 1) * 64;
  const int lrow = lane & 15;
  const int kbyte = (lane >> 4) * 16;           // byte offset within 128B LDS row
  f32x4 acc[4][4];
  #pragma unroll
  for (int i = 0; i < 4; ++i)
    #pragma unroll
    for (int j = 0; j < 4; ++j) { acc[i][j][0]=0.f; acc[i][j][1]=0.f; acc[i][j][2]=0.f; acc[i][j][3]=0.f; }

  for (int k0 = 0; k0 < K; k0 += 64) {
    #pragma unroll
    for (int p = 0; p < 4; ++p) {
      int c = p * 256 + tid;                    // 16B chunk index, linear LDS fill
      int row = c >> 3, colE = (c & 7) * 8;     // row, bf16-element col
      GLOAD_LDS(A + (size_t)(m0 + row) * K + k0 + colE, (char*)As + c * 16);
      GLOAD_LDS(B + (size_t)(n0 + row) * K + k0 + colE, (char*)Bs + c * 16);
    }
    __syncthreads();                            // vmcnt(0) drain of load_lds
    #pragma unroll
    for (int ks = 0; ks < 2; ++ks) {
      bf16x8 af[4], bfv[4];
      #pragma unroll
      for (int i = 0; i < 4; ++i) {
        af[i]  = *(const bf16x8*)((const char*)As + (wm + i * 16 + lrow) * 128 + ks * 64 + kbyte);
        bfv[i] = *(const bf16x8*)((const char*)Bs + (wn + i * 16 + lrow) * 128 + ks * 64 + kbyte);
      }
      #pragma unroll
      for (int i = 0; i < 4; ++i)
        #pragma unroll
        for (int j = 0; j < 4; ++j)
          acc[i][j] = __builtin_amdgcn_mfma_f32_16x16x32_bf16(af[i], bfv[j], acc[i][j], 0, 0, 0);
    }
    __syncthreads();
  }
  const int col = lane & 15;
  const int rbase = (lane >> 4) * 4;
  #pragma unroll
  for (int i = 0; i < 4; ++i)
    #pragma unroll
    for (int j = 0; j < 4; ++j) {
      int nn = n0 + wn + j * 16 + col;
      float bv = bias[nn];
      #pragma unroll
      for (int rr = 0; rr < 4; ++rr) {
        int mm = m0 + wm + i * 16 + rbase + rr;
        store_f32_sc(&D[(size_t)mm * N + nn], acc[i][j][rr] + bv);
      }
    }
}

// ---------------- ONE fused launch: LSTM + xp + logits(+sumexp) + finish ----------------
// [0,32): R7/R8 persistent LSTM producers (proven 5.06us/step) — unchanged.
// [32,544): xp tiles -> sc1 + xprow[rb]; producers poll xprow per 8 steps.
// [544,8544): logit tiles: poll mir >= 8(mt+1); GEMM; sc1 out stores; per-row
//   sumexp via butterfly + ONE AGENT atomicAdd into rsum; cnt_row[mt]++.
// [8544,9056): finish blocks (8 rows each): poll cnt_row[mt]==250;
//   out[row] -= log(rsum[row]) streaming pass. Replaces the 2-pass logsm.
// Deadlock-free: every poller's unlockers are strictly earlier in dispatch order.
__global__ __launch_bounds__(256) void k_fused(
    const float* __restrict__ xp_ro, float* __restrict__ xp,
    const __bf16* __restrict__ xb, const __bf16* __restrict__ wihb,
    const float* __restrict__ bias_sum, const float* __restrict__ Whh,
    __bf16* __restrict__ hs_full, int* __restrict__ cnt, int* __restrict__ mir,
    int* __restrict__ xprow, int* __restrict__ cnt_row, float* __restrict__ rsum,
    const __bf16* __restrict__ wlinb, float* __restrict__ out,
    const float* __restrict__ b_lin) {
  const int tid = threadIdx.x;
  const int bid = blockIdx.x;

  if (bid >= B_FIN0) {
    // ---------------- finish block: 8 rows, out -= log(rsum[row]) ----------------
    const int f  = bid - B_FIN0;                 // 0..511
    const int mt = f >> 4;
    __shared__ float lse_s[8];
    if (tid == 0) {
      while (load_cnt_sc(cnt_row + mt) < NTILE_N) __builtin_amdgcn_s_sleep(32);
    }
    __syncthreads();
    if (tid < 8) lse_s[tid] = __logf(load_f32_sc(rsum + f * 8 + tid));
    __syncthreads();
    #pragma unroll
    for (int rr = 0; rr < 8; ++rr) {
      float* p = out + (size_t)(f * 8 + rr) * VOCAB;
      const float lse = lse_s[rr];
      for (int i = tid; i < VOCAB / 4; i += 256) {
        float4 v = ((const float4*)p)[i];        // first-touch (deterministic data)
        v.x -= lse; v.y -= lse; v.z -= lse; v.w -= lse;
        ((float4*)p)[i] = v;                     // final: plain store
      }
    }
    return;
  }

  if (bid >= B_LOG0) {
    // ---------------- logit tile + in-register sumexp (R12-proven) ----------------
    __shared__ __align__(16) __bf16 As[128 * 64];
    __shared__ __align__(16) __bf16 Bs[128 * 64];
    const int t  = bid - B_LOG0;
    const int mt = t / NTILE_N, nt = t % NTILE_N;
    const int m0 = mt * 128, n0 = nt * 128;
    if (tid == 0) {
      const int need = 8 * (mt + 1);             // steps 8*mt .. 8*mt+7 complete
      int cur;
      while ((cur = load_cnt_sc(mir)) < need) {
        if (need - cur > 32) __builtin_amdgcn_s_sleep(64);
        else                 __builtin_amdgcn_s_sleep(8);
      }
    }
    __syncthreads();
    const __bf16* A = hs_full + BATCH * HDIM;    // hs rows m = s*16+b
    const int wave = tid >> 6, lane = tid & 63;
    const int wm = (wave >> 1) * 64, wn = (wave & 1) * 64;
    const int lrow = lane & 15;
    const int kbyte = (lane >> 4) * 16;
    f32x4 acc[4][4];
    #pragma unroll
    for (int i = 0; i < 4; ++i)
      #pragma unroll
      for (int j = 0; j < 4; ++j) { acc[i][j][0]=0.f; acc[i][j][1]=0.f; acc[i][j][2]=0.f; acc[i][j][3]=0.f; }
    for (int k0 = 0; k0 < HDIM; k0 += 64) {
      #pragma unroll
      for (int p = 0; p < 4; ++p) {
        int c = p * 256 + tid;
        int row = c >> 3, colE = (c & 7) * 8;
        GLOAD_LDS(A + (size_t)(m0 + row) * HDIM + k0 + colE, (char*)As + c * 16);
        GLOAD_LDS(wlinb + (size_t)(n0 + row) * HDIM + k0 + colE, (char*)Bs + c * 16);
      }
      __syncthreads();
      #pragma unroll
      for (int ks = 0; ks < 2; ++ks) {
        bf16x8 af[4], bfv[4];
        #pragma unroll
        for (int i = 0; i < 4; ++i) {
          af[i]  = *(const bf16x8*)((const char*)As + (wm + i * 16 + lrow) * 128 + ks * 64 + kbyte);
          bfv[i] = *(const bf16x8*)((const char*)Bs + (wn + i * 16 + lrow) * 128 + ks * 64 + kbyte);
        }
        #pragma unroll
        for (int i = 0; i < 4; ++i)
          #pragma unroll
          for (int j = 0; j < 4; ++j)
            acc[i][j] = __builtin_amdgcn_mfma_f32_16x16x32_bf16(af[i], bfv[j], acc[i][j], 0, 0, 0);
      }
      __syncthreads();
    }
    // epilogue: bias, sc1 logit store, per-row sumexp
    const int col = lane & 15;
    const int rbase = (lane >> 4) * 4;
    f32x4 rs[4];
    #pragma unroll
    for (int i = 0; i < 4; ++i) { rs[i][0]=0.f; rs[i][1]=0.f; rs[i][2]=0.f; rs[i][3]=0.f; }
    #pragma unroll
    for (int i = 0; i < 4; ++i)
      #pragma unroll
      for (int j = 0; j < 4; ++j) {
        int nn = n0 + wn + j * 16 + col;
        float bv = b_lin[nn];
        #pragma unroll
        for (int rr = 0; rr < 4; ++rr) {
          int mm = m0 + wm + i * 16 + rbase + rr;
          float v = acc[i][j][rr] + bv;
          store_f32_sc(&out[(size_t)mm * VOCAB + nn], v);
          rs[i][rr] += __expf(v);                // |v| <= ~23: no overflow
        }
      }
    #pragma unroll
    for (int off = 8; off > 0; off >>= 1)        // reduce across the 16 col-lanes
      #pragma unroll
      for (int i = 0; i < 4; ++i) {
        rs[i][0] += __shfl_xor(rs[i][0], off);
        rs[i][1] += __shfl_xor(rs[i][1], off);
        rs[i][2] += __shfl_xor(rs[i][2], off);
        rs[i][3] += __shfl_xor(rs[i][3], off);
      }
    if ((lane & 15) == 0) {
      #pragma unroll
      for (int i = 0; i < 4; ++i)
        #pragma unroll
        for (int rr = 0; rr < 4; ++rr)
          __hip_atomic_fetch_add(rsum + m0 + wm + i * 16 + rbase + rr,
                                 rs[i][rr], __ATOMIC_RELAXED, __HIP_MEMORY_SCOPE_AGENT);
    }
    __syncthreads();                             // drain sc1 stores + atomics (vmcnt 0)
    if (tid == 0)
      __hip_atomic_fetch_add(cnt_row + mt, 1, __ATOMIC_RELAXED, __HIP_MEMORY_SCOPE_AGENT);
    return;
  }

  if (bid >= B_XP0) {
    // ---------------- xp tile: xp[128,128] = xb * W_ih^T + bias ----------------
    __shared__ __align__(16) __bf16 As[128 * 64];
    __shared__ __align__(16) __bf16 Bs[128 * 64];
    const int t  = bid - B_XP0;
    const int rb = t >> 4, ntl = t & 15;         // row-block-major: earliest first
    gemm_tile_body(xb, wihb, xp, bias_sum, G4, EDIM, rb * 128, ntl * 128, As, Bs);
    __syncthreads();                             // drain sc1 xp-stores
    if (tid == 0)
      __hip_atomic_fetch_add(xprow + rb, 1, __ATOMIC_RELAXED, __HIP_MEMORY_SCOPE_AGENT);
    return;
  }

  // ---------------- producer: persistent LSTM (R7 structure, unchanged) ----------------
  __builtin_amdgcn_s_setprio(1);
  const int lane = tid & 63;
  const int wv   = tid >> 6;               // 0..3
  const int W    = bid * 4 + wv;           // 0..127
  const int c0   = W * 4;                  // first cell owned by this wave
  const int nl   = lane & 15;              // MFMA col (n_local) / A row (batch)
  const int g    = nl >> 2, cl = nl & 3;
  const int Grow = g * 512 + c0 + cl;      // gate row in [0,2048)
  const int kb   = (lane >> 4) * 8;        // per-lane K offset
  const int B0   = (lane >> 4) * 4;        // batch base of acc regs

  // ---- B-frags: W_hh[Grow][k], fp32 -> bf16, 64 VGPRs, loaded once ----
  bf16x8 bfrag[16];
  #pragma unroll
  for (int kk = 0; kk < 16; ++kk) {
    const float4* src = (const float4*)(Whh + (size_t)Grow * 512 + kk * 32 + kb);
    float4 w0 = src[0], w1 = src[1];
    bf16x8 tt = { (__bf16)w0.x, (__bf16)w0.y, (__bf16)w0.z, (__bf16)w0.w,
                  (__bf16)w1.x, (__bf16)w1.y, (__bf16)w1.z, (__bf16)w1.w };
    bfrag[kk] = tt;
  }

  // wait for xp row-block 0 (16 tiles), then prime xq
  while (load_cnt_sc(xprow) < 16) __builtin_amdgcn_s_sleep(2);
  float c_reg[4] = {0.f, 0.f, 0.f, 0.f};
  f32x4 xq;                                // xp[s][B0+r][Grow], prefetched
  #pragma unroll
  for (int r = 0; r < 4; ++r) xq[r] = xp_ro[(size_t)(B0 + r) * G4 + Grow];

  for (int s = 0; s < S_LEN; ++s) {
    // A-frags: h_s[batch=nl][k], 16B loads (first-touch; L3-resident slab)
    const __bf16* hrow = hs_full + (size_t)s * 8192 + nl * 512 + kb;
    bf16x8 afrag[16];
    #pragma unroll
    for (int kk = 0; kk < 16; ++kk)
      afrag[kk] = *(const bf16x8*)(hrow + kk * 32);

    f32x4 acc0 = xq;                       // C-in = input projection (incl. biases)
    f32x4 acc1 = {0.f, 0.f, 0.f, 0.f};
    #pragma unroll
    for (int kk = 0; kk < 16; kk += 2) {
      acc0 = __builtin_amdgcn_mfma_f32_16x16x32_bf16(afrag[kk],     bfrag[kk],     acc0, 0, 0, 0);
      acc1 = __builtin_amdgcn_mfma_f32_16x16x32_bf16(afrag[kk + 1], bfrag[kk + 1], acc1, 0, 0, 0);
    }

    // prefetch next step's xp while MFMA drains (poll xp row-block each 8 steps)
    if (s + 1 < S_LEN) {
      if (((s + 1) & 7) == 0) {
        const int* xr = xprow + ((s + 1) >> 3);
        while (load_cnt_sc(xr) < 16) __builtin_amdgcn_s_sleep(2);
      }
      const float* nx = xp_ro + ((size_t)(s + 1) * BATCH + B0) * G4 + Grow;
      #pragma unroll
      for (int r = 0; r < 4; ++r) xq[r] = nx[(size_t)r * G4];
    }

    f32x4 gates;
    #pragma unroll
    for (int r = 0; r < 4; ++r) gates[r] = acc0[r] + acc1[r];

    // redistribute: this lane takes i,f,g,o of cell c0+(lane&3), batches B0..B0+3
    const int lbase = (lane & 48) | (lane & 3);
    __bf16* dstbase = hs_full + (size_t)(s + 1) * 8192 + (size_t)B0 * 512 + c0 + (lane & 3);
    #pragma unroll
    for (int r = 0; r < 4; ++r) {
      float ig = __shfl(gates[r], lbase + 0);
      float fg = __shfl(gates[r], lbase + 4);
      float gg = __shfl(gates[r], lbase + 8);
      float og = __shfl(gates[r], lbase + 12);
      float si = 1.f / (1.f + __expf(-ig));
      float sf = 1.f / (1.f + __expf(-fg));
      float so = 1.f / (1.f + __expf(-og));
      float ag = fabsf(gg), eg = __expf(-2.f * ag);
      float tg = __builtin_copysignf((1.f - eg) / (1.f + eg), gg);
      float c  = sf * c_reg[r] + si * tg;
      c_reg[r] = c;
      float ac = fabsf(c), ec = __expf(-2.f * ac);
      float tc = __builtin_copysignf((1.f - ec) / (1.f + ec), c);
      float h  = so * tc;
      if ((lane & 12) == 0)                // 16 writer lanes: store as soon as computed
        store_short_sc(dstbase + (size_t)r * 512, (__bf16)h);
    }

    __syncthreads();                       // every wave drains its sc1 stores (vmcnt 0)
    if (tid == 0) {
      __hip_atomic_fetch_add(cnt, 1, __ATOMIC_RELAXED, __HIP_MEMORY_SCOPE_AGENT);
      const int target = NWG_LSTM * (s + 1);
      while (load_cnt_sc(cnt) < target) {}
      if (bid == 0)                        // fire-and-forget mirror for consumers
        store_int_sc(mir, s + 1);
    }
    __syncthreads();
  }
}

extern "C" void kernel_launch(void* const* d_in, const int* in_sizes, int n_in,
                              void* d_out, int out_size, void* d_ws, size_t ws_size,
                              hipStream_t stream) {
  const int*   tok   = (const int*)d_in[0];
  // d_in[1] = input_lengths: unused by the reference
  const float* embed = (const float*)d_in[2];
  const float* W_ih  = (const float*)d_in[3];
  const float* W_hh  = (const float*)d_in[4];
  const float* b_ih  = (const float*)d_in[5];
  const float* b_hh  = (const float*)d_in[6];
  const float* W_lin = (const float*)d_in[7];
  const float* b_lin = (const float*)d_in[8];
  float* out = (float*)d_out;
  char*  ws  = (char*)d_ws;

  int*    cnt      = (int*)(ws + OFF_CNT);
  int*    mir      = (int*)(ws + OFF_MIR);
  int*    xprow    = (int*)(ws + OFF_XPROW);
  int*    cnt_row  = (int*)(ws + OFF_CROW);
  float*  rsum     = (float*)(ws + OFF_RSUM);
  float*  bias_sum = (float*)(ws + OFF_BIAS);
  __bf16* xb       = (__bf16*)(ws + OFF_X);
  __bf16* wihb     = (__bf16*)(ws + OFF_WIH);
  __bf16* wlinb    = (__bf16*)(ws + OFF_WLIN);
  float*  xp       = (float*)(ws + OFF_XP);
  __bf16* hs_full  = (__bf16*)(ws + OFF_HS);

  // zero all counters + rsum + h_0 slab (required every replay; both small)
  hipMemsetAsync(ws, 0, OFF_BIAS, stream);
  hipMemsetAsync(ws + OFF_HS, 0, BATCH * HDIM * sizeof(__bf16), stream);

  k_prep<<<5128, 256, 0, stream>>>(tok, embed, xb, W_ih, wihb, W_lin, wlinb,
                                   b_ih, b_hh, bias_sum);
  k_fused<<<NB_ALL, 256, 0, stream>>>(xp, xp, xb, wihb, bias_sum, W_hh, hs_full,
                                      cnt, mir, xprow, cnt_row, rsum, wlinb,
                                      out, b_lin);
}

// Round 14
// 2899.235 us; speedup vs baseline: 1.5873x; 1.0078x over previous
//
#include <hip/hip_runtime.h>
#include <hip/hip_bf16.h>

typedef __bf16 bf16x8 __attribute__((ext_vector_type(8)));
typedef __bf16 bf16x4 __attribute__((ext_vector_type(4)));
typedef float  f32x4  __attribute__((ext_vector_type(4)));

#define S_LEN  256
#define BATCH  16
#define EDIM   512
#define HDIM   512
#define VOCAB  32000
#define G4     2048          // 4*H
#define M_ROWS 4096          // S*B
#define NWG_LSTM 32
#define NTILE_N  (VOCAB / 128)   // 250 logit n-tiles
#define NTILE_M  (M_ROWS / 128)  // 32 logit m-tiles

// fused-launch block partition (order = dependency order; in-order dispatch)
#define NB_PROD NWG_LSTM
#define NB_XP   512                  // 32 rb x 16 nt
#define NB_LOG  (NTILE_M * NTILE_N)  // 8000 logit tiles
#define NB_FIN  512                  // 512 finish blocks x 8 rows
#define B_XP0   NB_PROD
#define B_LOG0  (B_XP0 + NB_XP)
#define B_FIN0  (B_LOG0 + NB_LOG)
#define NB_ALL  (B_FIN0 + NB_FIN)    // 9056

// ------- ws layout (bytes) -------
// COUNTER RULE: all counters/accumulators are L3-scope (AGENT atomics or
// sc0sc1 ops) so the in-graph memset resets them every replay (R9 lesson:
// no-scope atomics leave dirty L2 lines memset can't reach).
#define OFF_CNT   0                         // int: LSTM step barrier counter
#define OFF_MIR   256                       // int: published completed-step count
#define OFF_XPROW 512                       // int[32]: xp tiles done per row-block
#define OFF_CROW  1024                      // int[32]: logit tiles done per row-block
#define OFF_RSUM  4096                      // float[4096]: per-row sum of exp(logit)
#define OFF_BIAS  20480                     // float[2048] = b_ih + b_hh
#define OFF_X     28672                     // bf16[4096*512] gathered embeddings
#define OFF_WIH   (OFF_X + 4194304)         // bf16[2048*512]
#define OFF_WLIN  (OFF_WIH + 2097152)       // bf16[32000*512]
#define OFF_XP    (OFF_WLIN + 32768000)     // float[4096*2048]
#define OFF_HS    (OFF_XP + 33554432)       // bf16[257*16*512]; slab 0 zeroed (h_0)
// total = 76,853,248 bytes

// ---- device-coherent (write-through to Infinity Cache, L3-scope) ops ----
__device__ __forceinline__ void store_short_sc(__bf16* p, __bf16 v) {
  unsigned short u = __builtin_bit_cast(unsigned short, v);
  asm volatile("global_store_short %0, %1, off sc0 sc1" :: "v"(p), "v"(u) : "memory");
}
__device__ __forceinline__ void store_f32_sc(float* p, float v) {
  asm volatile("global_store_dword %0, %1, off sc0 sc1" :: "v"(p), "v"(v) : "memory");
}
__device__ __forceinline__ void store_int_sc(int* p, int v) {
  asm volatile("global_store_dword %0, %1, off sc0 sc1" :: "v"(p), "v"(v) : "memory");
}
__device__ __forceinline__ int load_cnt_sc(const int* p) {   // L3-coherent read
  int r;
  asm volatile("global_load_dword %0, %1, off sc0 sc1\n\ts_waitcnt vmcnt(0)"
               : "=v"(r) : "v"(p) : "memory");
  return r;
}
__device__ __forceinline__ float load_f32_sc(const float* p) {
  float r;
  asm volatile("global_load_dword %0, %1, off sc0 sc1\n\ts_waitcnt vmcnt(0)"
               : "=v"(r) : "v"(p) : "memory");
  return r;
}

#define GLOAD_LDS(gsrc, ldst)                                                  \
  __builtin_amdgcn_global_load_lds(                                            \
      (const __attribute__((address_space(1))) void*)(gsrc),                   \
      (__attribute__((address_space(3))) void*)(ldst), 16, 0, 0)

// ---------------- merged prep kernel (separate launch; kernel-boundary
// coherence covers the handoff to k_fused) ----------------
__global__ __launch_bounds__(256) void k_prep(
    const int* __restrict__ tok, const float* __restrict__ embed, __bf16* __restrict__ xb,
    const float* __restrict__ W_ih, __bf16* __restrict__ wihb,
    const float* __restrict__ W_lin, __bf16* __restrict__ wlinb,
    const float* __restrict__ b_ih, const float* __restrict__ b_hh, float* __restrict__ bb) {
  const int b = blockIdx.x, tid = threadIdx.x;
  if (b < 2048) {                       // embedding gather+cast: 4096*128 float4 chunks
    int i = b * 256 + tid;
    int m = i >> 7, c = i & 127;
    int t = tok[m];
    float4 v = ((const float4*)(embed + (size_t)t * EDIM))[c];
    bf16x4 o = { (__bf16)v.x, (__bf16)v.y, (__bf16)v.z, (__bf16)v.w };
    ((bf16x4*)(xb + (size_t)m * EDIM))[c] = o;
  } else if (b < 3072) {                // W_ih cast: 262144 float4
    int i = (b - 2048) * 256 + tid;
    float4 v = ((const float4*)W_ih)[i];
    bf16x4 o = { (__bf16)v.x, (__bf16)v.y, (__bf16)v.z, (__bf16)v.w };
    ((bf16x4*)wihb)[i] = o;
  } else if (b < 5120) {                // W_lin cast: 4,096,000 float4, grid-stride
    for (int i = (b - 3072) * 256 + tid; i < VOCAB * HDIM / 4; i += 2048 * 256) {
      float4 v = ((const float4*)W_lin)[i];
      bf16x4 o = { (__bf16)v.x, (__bf16)v.y, (__bf16)v.z, (__bf16)v.w };
      ((bf16x4*)wlinb)[i] = o;
    }
  } else {                              // bias sum
    int i = (b - 5120) * 256 + tid;
    if (i < G4) bb[i] = b_ih[i] + b_hh[i];
  }
}

// ------- shared 128x128 MFMA GEMM tile body: D = A[M,K]*B[N,K]^T + bias -------
// sc1 stores: results land in coherent L3 for same-launch cross-XCD readers.
__device__ __forceinline__ void gemm_tile_body(
    const __bf16* __restrict__ A, const __bf16* __restrict__ B,
    float* __restrict__ D, const float* __restrict__ bias,
    int N, int K, int m0, int n0, __bf16* As, __bf16* Bs) {
  const int tid  = threadIdx.x;
  const int wave = tid >> 6, lane = tid & 63;
  const int wm   = (wave >> 1) * 64, wn = (wave & 1) * 64;
  const int lrow = lane & 15;
  const int kbyte = (lane >> 4) * 16;           // byte offset within 128B LDS row
  f32x4 acc[4][4];
  #pragma unroll
  for (int i = 0; i < 4; ++i)
    #pragma unroll
    for (int j = 0; j < 4; ++j) { acc[i][j][0]=0.f; acc[i][j][1]=0.f; acc[i][j][2]=0.f; acc[i][j][3]=0.f; }

  for (int k0 = 0; k0 < K; k0 += 64) {
    #pragma unroll
    for (int p = 0; p < 4; ++p) {
      int c = p * 256 + tid;                    // 16B chunk index, linear LDS fill
      int row = c >> 3, colE = (c & 7) * 8;     // row, bf16-element col
      GLOAD_LDS(A + (size_t)(m0 + row) * K + k0 + colE, (char*)As + c * 16);
      GLOAD_LDS(B + (size_t)(n0 + row) * K + k0 + colE, (char*)Bs + c * 16);
    }
    __syncthreads();                            // vmcnt(0) drain of load_lds
    #pragma unroll
    for (int ks = 0; ks < 2; ++ks) {
      bf16x8 af[4], bfv[4];
      #pragma unroll
      for (int i = 0; i < 4; ++i) {
        af[i]  = *(const bf16x8*)((const char*)As + (wm + i * 16 + lrow) * 128 + ks * 64 + kbyte);
        bfv[i] = *(const bf16x8*)((const char*)Bs + (wn + i * 16 + lrow) * 128 + ks * 64 + kbyte);
      }
      #pragma unroll
      for (int i = 0; i < 4; ++i)
        #pragma unroll
        for (int j = 0; j < 4; ++j)
          acc[i][j] = __builtin_amdgcn_mfma_f32_16x16x32_bf16(af[i], bfv[j], acc[i][j], 0, 0, 0);
    }
    __syncthreads();
  }
  const int col = lane & 15;
  const int rbase = (lane >> 4) * 4;
  #pragma unroll
  for (int i = 0; i < 4; ++i)
    #pragma unroll
    for (int j = 0; j < 4; ++j) {
      int nn = n0 + wn + j * 16 + col;
      float bv = bias[nn];
      #pragma unroll
      for (int rr = 0; rr < 4; ++rr) {
        int mm = m0 + wm + i * 16 + rbase + rr;
        store_f32_sc(&D[(size_t)mm * N + nn], acc[i][j][rr] + bv);
      }
    }
}

// ---------------- ONE fused launch: LSTM + xp + logits(+sumexp) + finish ----------------
// [0,32): R7/R8 persistent LSTM producers (proven 5.06us/step) — unchanged.
// [32,544): xp tiles -> sc1 + xprow[rb]; producers poll xprow per 8 steps.
// [544,8544): logit tiles: poll mir >= 8(mt+1); GEMM; sc1 out stores; per-row
//   sumexp via butterfly + ONE AGENT atomicAdd into rsum; cnt_row[mt]++.
// [8544,9056): finish blocks (8 rows each): poll cnt_row[mt]==250;
//   out[row] -= log(rsum[row]) streaming pass. Replaces the 2-pass logsm.
// LDS RULE (R13 lesson): __shared__ is statically SUMMED across branch
// scopes -> declare ONE As/Bs at kernel scope (33KB total, 4 blocks/CU).
__global__ __launch_bounds__(256) void k_fused(
    const float* __restrict__ xp_ro, float* __restrict__ xp,
    const __bf16* __restrict__ xb, const __bf16* __restrict__ wihb,
    const float* __restrict__ bias_sum, const float* __restrict__ Whh,
    __bf16* __restrict__ hs_full, int* __restrict__ cnt, int* __restrict__ mir,
    int* __restrict__ xprow, int* __restrict__ cnt_row, float* __restrict__ rsum,
    const __bf16* __restrict__ wlinb, float* __restrict__ out,
    const float* __restrict__ b_lin) {
  __shared__ __align__(16) __bf16 As[128 * 64];   // single copy, all branches
  __shared__ __align__(16) __bf16 Bs[128 * 64];
  const int tid = threadIdx.x;
  const int bid = blockIdx.x;

  if (bid >= B_FIN0) {
    // ---------------- finish block: 8 rows, out -= log(rsum[row]) ----------------
    const int f  = bid - B_FIN0;                 // 0..511
    const int mt = f >> 4;
    __shared__ float lse_s[8];
    if (tid == 0) {
      while (load_cnt_sc(cnt_row + mt) < NTILE_N) __builtin_amdgcn_s_sleep(32);
    }
    __syncthreads();
    if (tid < 8) lse_s[tid] = __logf(load_f32_sc(rsum + f * 8 + tid));
    __syncthreads();
    #pragma unroll
    for (int rr = 0; rr < 8; ++rr) {
      float* p = out + (size_t)(f * 8 + rr) * VOCAB;
      const float lse = lse_s[rr];
      for (int i = tid; i < VOCAB / 4; i += 256) {
        float4 v = ((const float4*)p)[i];        // first-touch (deterministic data)
        v.x -= lse; v.y -= lse; v.z -= lse; v.w -= lse;
        ((float4*)p)[i] = v;                     // final: plain store
      }
    }
    return;
  }

  if (bid >= B_LOG0) {
    // ---------------- logit tile + in-register sumexp (R12-proven) ----------------
    const int t  = bid - B_LOG0;
    const int mt = t / NTILE_N, nt = t % NTILE_N;
    const int m0 = mt * 128, n0 = nt * 128;
    if (tid == 0) {
      const int need = 8 * (mt + 1);             // steps 8*mt .. 8*mt+7 complete
      int cur;
      while ((cur = load_cnt_sc(mir)) < need) {
        if (need - cur > 32) __builtin_amdgcn_s_sleep(64);
        else                 __builtin_amdgcn_s_sleep(8);
      }
    }
    __syncthreads();
    const __bf16* A = hs_full + BATCH * HDIM;    // hs rows m = s*16+b
    const int wave = tid >> 6, lane = tid & 63;
    const int wm = (wave >> 1) * 64, wn = (wave & 1) * 64;
    const int lrow = lane & 15;
    const int kbyte = (lane >> 4) * 16;
    f32x4 acc[4][4];
    #pragma unroll
    for (int i = 0; i < 4; ++i)
      #pragma unroll
      for (int j = 0; j < 4; ++j) { acc[i][j][0]=0.f; acc[i][j][1]=0.f; acc[i][j][2]=0.f; acc[i][j][3]=0.f; }
    for (int k0 = 0; k0 < HDIM; k0 += 64) {
      #pragma unroll
      for (int p = 0; p < 4; ++p) {
        int c = p * 256 + tid;
        int row = c >> 3, colE = (c & 7) * 8;
        GLOAD_LDS(A + (size_t)(m0 + row) * HDIM + k0 + colE, (char*)As + c * 16);
        GLOAD_LDS(wlinb + (size_t)(n0 + row) * HDIM + k0 + colE, (char*)Bs + c * 16);
      }
      __syncthreads();
      #pragma unroll
      for (int ks = 0; ks < 2; ++ks) {
        bf16x8 af[4], bfv[4];
        #pragma unroll
        for (int i = 0; i < 4; ++i) {
          af[i]  = *(const bf16x8*)((const char*)As + (wm + i * 16 + lrow) * 128 + ks * 64 + kbyte);
          bfv[i] = *(const bf16x8*)((const char*)Bs + (wn + i * 16 + lrow) * 128 + ks * 64 + kbyte);
        }
        #pragma unroll
        for (int i = 0; i < 4; ++i)
          #pragma unroll
          for (int j = 0; j < 4; ++j)
            acc[i][j] = __builtin_amdgcn_mfma_f32_16x16x32_bf16(af[i], bfv[j], acc[i][j], 0, 0, 0);
      }
      __syncthreads();
    }
    // epilogue: bias, sc1 logit store, per-row sumexp
    const int col = lane & 15;
    const int rbase = (lane >> 4) * 4;
    f32x4 rs[4];
    #pragma unroll
    for (int i = 0; i < 4; ++i) { rs[i][0]=0.f; rs[i][1]=0.f; rs[i][2]=0.f; rs[i][3]=0.f; }
    #pragma unroll
    for (int i = 0; i < 4; ++i)
      #pragma unroll
      for (int j = 0; j < 4; ++j) {
        int nn = n0 + wn + j * 16 + col;
        float bv = b_lin[nn];
        #pragma unroll
        for (int rr = 0; rr < 4; ++rr) {
          int mm = m0 + wm + i * 16 + rbase + rr;
          float v = acc[i][j][rr] + bv;
          store_f32_sc(&out[(size_t)mm * VOCAB + nn], v);
          rs[i][rr] += __expf(v);                // |v| <= ~23: no overflow
        }
      }
    #pragma unroll
    for (int off = 8; off > 0; off >>= 1)        // reduce across the 16 col-lanes
      #pragma unroll
      for (int i = 0; i < 4; ++i) {
        rs[i][0] += __shfl_xor(rs[i][0], off);
        rs[i][1] += __shfl_xor(rs[i][1], off);
        rs[i][2] += __shfl_xor(rs[i][2], off);
        rs[i][3] += __shfl_xor(rs[i][3], off);
      }
    if ((lane & 15) == 0) {
      #pragma unroll
      for (int i = 0; i < 4; ++i)
        #pragma unroll
        for (int rr = 0; rr < 4; ++rr)
          __hip_atomic_fetch_add(rsum + m0 + wm + i * 16 + rbase + rr,
                                 rs[i][rr], __ATOMIC_RELAXED, __HIP_MEMORY_SCOPE_AGENT);
    }
    __syncthreads();                             // drain sc1 stores + atomics (vmcnt 0)
    if (tid == 0)
      __hip_atomic_fetch_add(cnt_row + mt, 1, __ATOMIC_RELAXED, __HIP_MEMORY_SCOPE_AGENT);
    return;
  }

  if (bid >= B_XP0) {
    // ---------------- xp tile: xp[128,128] = xb * W_ih^T + bias ----------------
    const int t  = bid - B_XP0;
    const int rb = t >> 4, ntl = t & 15;         // row-block-major: earliest first
    gemm_tile_body(xb, wihb, xp, bias_sum, G4, EDIM, rb * 128, ntl * 128, As, Bs);
    __syncthreads();                             // drain sc1 xp-stores
    if (tid == 0)
      __hip_atomic_fetch_add(xprow + rb, 1, __ATOMIC_RELAXED, __HIP_MEMORY_SCOPE_AGENT);
    return;
  }

  // ---------------- producer: persistent LSTM (R7 structure, unchanged) ----------------
  __builtin_amdgcn_s_setprio(1);
  const int lane = tid & 63;
  const int wv   = tid >> 6;               // 0..3
  const int W    = bid * 4 + wv;           // 0..127
  const int c0   = W * 4;                  // first cell owned by this wave
  const int nl   = lane & 15;              // MFMA col (n_local) / A row (batch)
  const int g    = nl >> 2, cl = nl & 3;
  const int Grow = g * 512 + c0 + cl;      // gate row in [0,2048)
  const int kb   = (lane >> 4) * 8;        // per-lane K offset
  const int B0   = (lane >> 4) * 4;        // batch base of acc regs

  // ---- B-frags: W_hh[Grow][k], fp32 -> bf16, 64 VGPRs, loaded once ----
  bf16x8 bfrag[16];
  #pragma unroll
  for (int kk = 0; kk < 16; ++kk) {
    const float4* src = (const float4*)(Whh + (size_t)Grow * 512 + kk * 32 + kb);
    float4 w0 = src[0], w1 = src[1];
    bf16x8 tt = { (__bf16)w0.x, (__bf16)w0.y, (__bf16)w0.z, (__bf16)w0.w,
                  (__bf16)w1.x, (__bf16)w1.y, (__bf16)w1.z, (__bf16)w1.w };
    bfrag[kk] = tt;
  }

  // wait for xp row-block 0 (16 tiles), then prime xq
  while (load_cnt_sc(xprow) < 16) __builtin_amdgcn_s_sleep(2);
  float c_reg[4] = {0.f, 0.f, 0.f, 0.f};
  f32x4 xq;                                // xp[s][B0+r][Grow], prefetched
  #pragma unroll
  for (int r = 0; r < 4; ++r) xq[r] = xp_ro[(size_t)(B0 + r) * G4 + Grow];

  for (int s = 0; s < S_LEN; ++s) {
    // A-frags: h_s[batch=nl][k], 16B loads (first-touch; L3-resident slab)
    const __bf16* hrow = hs_full + (size_t)s * 8192 + nl * 512 + kb;
    bf16x8 afrag[16];
    #pragma unroll
    for (int kk = 0; kk < 16; ++kk)
      afrag[kk] = *(const bf16x8*)(hrow + kk * 32);

    f32x4 acc0 = xq;                       // C-in = input projection (incl. biases)
    f32x4 acc1 = {0.f, 0.f, 0.f, 0.f};
    #pragma unroll
    for (int kk = 0; kk < 16; kk += 2) {
      acc0 = __builtin_amdgcn_mfma_f32_16x16x32_bf16(afrag[kk],     bfrag[kk],     acc0, 0, 0, 0);
      acc1 = __builtin_amdgcn_mfma_f32_16x16x32_bf16(afrag[kk + 1], bfrag[kk + 1], acc1, 0, 0, 0);
    }

    // prefetch next step's xp while MFMA drains (poll xp row-block each 8 steps)
    if (s + 1 < S_LEN) {
      if (((s + 1) & 7) == 0) {
        const int* xr = xprow + ((s + 1) >> 3);
        while (load_cnt_sc(xr) < 16) __builtin_amdgcn_s_sleep(2);
      }
      const float* nx = xp_ro + ((size_t)(s + 1) * BATCH + B0) * G4 + Grow;
      #pragma unroll
      for (int r = 0; r < 4; ++r) xq[r] = nx[(size_t)r * G4];
    }

    f32x4 gates;
    #pragma unroll
    for (int r = 0; r < 4; ++r) gates[r] = acc0[r] + acc1[r];

    // redistribute: this lane takes i,f,g,o of cell c0+(lane&3), batches B0..B0+3
    const int lbase = (lane & 48) | (lane & 3);
    __bf16* dstbase = hs_full + (size_t)(s + 1) * 8192 + (size_t)B0 * 512 + c0 + (lane & 3);
    #pragma unroll
    for (int r = 0; r < 4; ++r) {
      float ig = __shfl(gates[r], lbase + 0);
      float fg = __shfl(gates[r], lbase + 4);
      float gg = __shfl(gates[r], lbase + 8);
      float og = __shfl(gates[r], lbase + 12);
      float si = 1.f / (1.f + __expf(-ig));
      float sf = 1.f / (1.f + __expf(-fg));
      float so = 1.f / (1.f + __expf(-og));
      float ag = fabsf(gg), eg = __expf(-2.f * ag);
      float tg = __builtin_copysignf((1.f - eg) / (1.f + eg), gg);
      float c  = sf * c_reg[r] + si * tg;
      c_reg[r] = c;
      float ac = fabsf(c), ec = __expf(-2.f * ac);
      float tc = __builtin_copysignf((1.f - ec) / (1.f + ec), c);
      float h  = so * tc;
      if ((lane & 12) == 0)                // 16 writer lanes: store as soon as computed
        store_short_sc(dstbase + (size_t)r * 512, (__bf16)h);
    }

    __syncthreads();                       // every wave drains its sc1 stores (vmcnt 0)
    if (tid == 0) {
      __hip_atomic_fetch_add(cnt, 1, __ATOMIC_RELAXED, __HIP_MEMORY_SCOPE_AGENT);
      const int target = NWG_LSTM * (s + 1);
      while (load_cnt_sc(cnt) < target) {}
      if (bid == 0)                        // fire-and-forget mirror for consumers
        store_int_sc(mir, s + 1);
    }
    __syncthreads();
  }
}

extern "C" void kernel_launch(void* const* d_in, const int* in_sizes, int n_in,
                              void* d_out, int out_size, void* d_ws, size_t ws_size,
                              hipStream_t stream) {
  const int*   tok   = (const int*)d_in[0];
  // d_in[1] = input_lengths: unused by the reference
  const float* embed = (const float*)d_in[2];
  const float* W_ih  = (const float*)d_in[3];
  const float* W_hh  = (const float*)d_in[4];
  const float* b_ih  = (const float*)d_in[5];
  const float* b_hh  = (const float*)d_in[6];
  const float* W_lin = (const float*)d_in[7];
  const float* b_lin = (const float*)d_in[8];
  float* out = (float*)d_out;
  char*  ws  = (char*)d_ws;

  int*    cnt      = (int*)(ws + OFF_CNT);
  int*    mir      = (int*)(ws + OFF_MIR);
  int*    xprow    = (int*)(ws + OFF_XPROW);
  int*    cnt_row  = (int*)(ws + OFF_CROW);
  float*  rsum     = (float*)(ws + OFF_RSUM);
  float*  bias_sum = (float*)(ws + OFF_BIAS);
  __bf16* xb       = (__bf16*)(ws + OFF_X);
  __bf16* wihb     = (__bf16*)(ws + OFF_WIH);
  __bf16* wlinb    = (__bf16*)(ws + OFF_WLIN);
  float*  xp       = (float*)(ws + OFF_XP);
  __bf16* hs_full  = (__bf16*)(ws + OFF_HS);

  // zero all counters + rsum + h_0 slab (required every replay; both small)
  hipMemsetAsync(ws, 0, OFF_BIAS, stream);
  hipMemsetAsync(ws + OFF_HS, 0, BATCH * HDIM * sizeof(__bf16), stream);

  k_prep<<<5128, 256, 0, stream>>>(tok, embed, xb, W_ih, wihb, W_lin, wlinb,
                                   b_ih, b_hh, bias_sum);
  k_fused<<<NB_ALL, 256, 0, stream>>>(xp, xp, xb, wihb, bias_sum, W_hh, hs_full,
                                      cnt, mir, xprow, cnt_row, rsum, wlinb,
                                      out, b_lin);
}

// Round 15
// 1639.935 us; speedup vs baseline: 2.8061x; 1.7679x over previous
//
#include <hip/hip_runtime.h>
#include <hip/hip_bf16.h>

typedef __bf16 bf16x8 __attribute__((ext_vector_type(8)));
typedef __bf16 bf16x4 __attribute__((ext_vector_type(4)));
typedef float  f32x4  __attribute__((ext_vector_type(4)));

#define S_LEN  256
#define BATCH  16
#define EDIM   512
#define HDIM   512
#define VOCAB  32000
#define G4     2048          // 4*H
#define M_ROWS 4096          // S*B
#define NWG_LSTM 32
#define NTILE_N  (VOCAB / 128)   // 250 consumer n-tiles
#define NTILE_M  (M_ROWS / 128)  // 32 consumer m-tiles

// ------- ws layout (bytes) -------
#define OFF_CNT   0                         // int: LSTM step barrier counter
#define OFF_MIR   256                       // int: mirror of completed steps (own line)
#define OFF_BIAS  4096                      // float[2048] = b_ih + b_hh
#define OFF_X     12288                     // bf16[4096*512] gathered embeddings
#define OFF_WIH   (OFF_X + 4194304)         // bf16[2048*512]
#define OFF_WLIN  (OFF_WIH + 2097152)       // bf16[32000*512]
#define OFF_XP    (OFF_WLIN + 32768000)     // float[4096*2048]
#define OFF_HS    (OFF_XP + 33554432)       // bf16[257*16*512]; slab 0 zeroed (h_0)
// total = 76,836,864 bytes

// ---- device-coherent (write-through to Infinity Cache) ops ----
__device__ __forceinline__ void store_short_sc(__bf16* p, __bf16 v) {
  unsigned short u = __builtin_bit_cast(unsigned short, v);
  asm volatile("global_store_short %0, %1, off sc0 sc1" :: "v"(p), "v"(u) : "memory");
}
__device__ __forceinline__ void store_int_sc(int* p, int v) {
  asm volatile("global_store_dword %0, %1, off sc0 sc1" :: "v"(p), "v"(v) : "memory");
}
__device__ __forceinline__ int load_cnt_sc(const int* p) {
  int r;
  asm volatile("global_load_dword %0, %1, off sc0 sc1\n\ts_waitcnt vmcnt(0)"
               : "=v"(r) : "v"(p) : "memory");
  return r;
}

#define GLOAD_LDS(gsrc, ldst)                                                  \
  __builtin_amdgcn_global_load_lds(                                            \
      (const __attribute__((address_space(1))) void*)(gsrc),                   \
      (__attribute__((address_space(3))) void*)(ldst), 16, 0, 0)

// ---------------- merged prep kernel (one launch; proven R11/R13/R14) ----------------
__global__ __launch_bounds__(256) void k_prep(
    const int* __restrict__ tok, const float* __restrict__ embed, __bf16* __restrict__ xb,
    const float* __restrict__ W_ih, __bf16* __restrict__ wihb,
    const float* __restrict__ W_lin, __bf16* __restrict__ wlinb,
    const float* __restrict__ b_ih, const float* __restrict__ b_hh, float* __restrict__ bb) {
  const int b = blockIdx.x, tid = threadIdx.x;
  if (b < 2048) {                       // embedding gather+cast: 4096*128 float4 chunks
    int i = b * 256 + tid;
    int m = i >> 7, c = i & 127;
    int t = tok[m];
    float4 v = ((const float4*)(embed + (size_t)t * EDIM))[c];
    bf16x4 o = { (__bf16)v.x, (__bf16)v.y, (__bf16)v.z, (__bf16)v.w };
    ((bf16x4*)(xb + (size_t)m * EDIM))[c] = o;
  } else if (b < 3072) {                // W_ih cast: 262144 float4
    int i = (b - 2048) * 256 + tid;
    float4 v = ((const float4*)W_ih)[i];
    bf16x4 o = { (__bf16)v.x, (__bf16)v.y, (__bf16)v.z, (__bf16)v.w };
    ((bf16x4*)wihb)[i] = o;
  } else if (b < 5120) {                // W_lin cast: 4,096,000 float4, grid-stride
    for (int i = (b - 3072) * 256 + tid; i < VOCAB * HDIM / 4; i += 2048 * 256) {
      float4 v = ((const float4*)W_lin)[i];
      bf16x4 o = { (__bf16)v.x, (__bf16)v.y, (__bf16)v.z, (__bf16)v.w };
      ((bf16x4*)wlinb)[i] = o;
    }
  } else {                              // bias sum
    int i = (b - 5120) * 256 + tid;
    if (i < G4) bb[i] = b_ih[i] + b_hh[i];
  }
}

// ------- shared 128x128 MFMA GEMM tile body: D = A[M,K]*B[N,K]^T + bias -------
__device__ __forceinline__ void gemm_tile_body(
    const __bf16* __restrict__ A, const __bf16* __restrict__ B,
    float* __restrict__ D, const float* __restrict__ bias,
    int N, int K, int m0, int n0, __bf16* As, __bf16* Bs) {
  const int tid  = threadIdx.x;
  const int wave = tid >> 6, lane = tid & 63;
  const int wm   = (wave >> 1) * 64, wn = (wave & 1) * 64;
  const int lrow = lane & 15;
  const int kbyte = (lane >> 4) * 16;           // byte offset within 128B LDS row
  f32x4 acc[4][4];
  #pragma unroll
  for (int i = 0; i < 4; ++i)
    #pragma unroll
    for (int j = 0; j < 4; ++j) { acc[i][j][0]=0.f; acc[i][j][1]=0.f; acc[i][j][2]=0.f; acc[i][j][3]=0.f; }

  for (int k0 = 0; k0 < K; k0 += 64) {
    #pragma unroll
    for (int p = 0; p < 4; ++p) {
      int c = p * 256 + tid;                    // 16B chunk index, linear LDS fill
      int row = c >> 3, colE = (c & 7) * 8;     // row, bf16-element col
      GLOAD_LDS(A + (size_t)(m0 + row) * K + k0 + colE, (char*)As + c * 16);
      GLOAD_LDS(B + (size_t)(n0 + row) * K + k0 + colE, (char*)Bs + c * 16);
    }
    __syncthreads();                            // vmcnt(0) drain of load_lds
    #pragma unroll
    for (int ks = 0; ks < 2; ++ks) {
      bf16x8 af[4], bfv[4];
      #pragma unroll
      for (int i = 0; i < 4; ++i) {
        af[i]  = *(const bf16x8*)((const char*)As + (wm + i * 16 + lrow) * 128 + ks * 64 + kbyte);
        bfv[i] = *(const bf16x8*)((const char*)Bs + (wn + i * 16 + lrow) * 128 + ks * 64 + kbyte);
      }
      #pragma unroll
      for (int i = 0; i < 4; ++i)
        #pragma unroll
        for (int j = 0; j < 4; ++j)
          acc[i][j] = __builtin_amdgcn_mfma_f32_16x16x32_bf16(af[i], bfv[j], acc[i][j], 0, 0, 0);
    }
    __syncthreads();
  }
  const int col = lane & 15;
  const int rbase = (lane >> 4) * 4;
  #pragma unroll
  for (int i = 0; i < 4; ++i)
    #pragma unroll
    for (int j = 0; j < 4; ++j) {
      int nn = n0 + wn + j * 16 + col;
      float bv = bias[nn];
      #pragma unroll
      for (int rr = 0; rr < 4; ++rr) {
        int mm = m0 + wm + i * 16 + rbase + rr;
        D[(size_t)mm * N + nn] = acc[i][j][rr] + bv;
      }
    }
}

// standalone GEMM (xp projection)
__global__ __launch_bounds__(256) void k_gemm2(
    const __bf16* __restrict__ A, const __bf16* __restrict__ B,
    float* __restrict__ D, const float* __restrict__ bias, int N, int K) {
  __shared__ __align__(16) __bf16 As[128 * 64];
  __shared__ __align__(16) __bf16 Bs[128 * 64];
  gemm_tile_body(A, B, D, bias, N, K, blockIdx.y * 128, blockIdx.x * 128, As, Bs);
}

// ---------------- fused persistent LSTM + polling logits GEMM (R7, proven) ----------------
// Blocks [0,32): persistent MFMA LSTM (5.06us/step measured).
// Blocks [32, 32+8000): logit GEMM tiles; poll mir >= 8(mt+1) then normal GEMM.
// Every hs line is first-touched on any XCD only after its step is final, so
// normal cached loads are safe. Producers never wait on consumers.
__global__ __launch_bounds__(256) void k_lstm_fused(
    const float* __restrict__ xp, const float* __restrict__ Whh,
    __bf16* __restrict__ hs_full, int* __restrict__ cnt, int* __restrict__ mir,
    const __bf16* __restrict__ wlinb, float* __restrict__ out,
    const float* __restrict__ b_lin) {
  __shared__ __align__(16) __bf16 As[128 * 64];
  __shared__ __align__(16) __bf16 Bs[128 * 64];
  const int tid = threadIdx.x;

  if (blockIdx.x >= NWG_LSTM) {
    // ---------------- consumer: one 128x128 logits tile ----------------
    const int t  = blockIdx.x - NWG_LSTM;
    const int mt = t / NTILE_N, nt = t % NTILE_N;
    if (tid == 0) {
      const int need = 8 * (mt + 1);           // steps 8*mt .. 8*mt+7 complete
      while (load_cnt_sc(mir) < need) __builtin_amdgcn_s_sleep(16);
    }
    __syncthreads();
    gemm_tile_body(hs_full + BATCH * HDIM, wlinb, out, b_lin,
                   VOCAB, HDIM, mt * 128, nt * 128, As, Bs);
    return;
  }

  // ---------------- producer: persistent LSTM ----------------
  __builtin_amdgcn_s_setprio(1);
  const int lane = tid & 63;
  const int wv   = tid >> 6;               // 0..3
  const int W    = blockIdx.x * 4 + wv;    // 0..127
  const int c0   = W * 4;                  // first cell owned by this wave
  const int nl   = lane & 15;              // MFMA col (n_local) / A row (batch)
  const int g    = nl >> 2, cl = nl & 3;
  const int Grow = g * 512 + c0 + cl;      // gate row in [0,2048)
  const int kb   = (lane >> 4) * 8;        // per-lane K offset
  const int B0   = (lane >> 4) * 4;        // batch base of acc regs

  // ---- B-frags: W_hh[Grow][k], fp32 -> bf16, 64 VGPRs, loaded once ----
  bf16x8 bfrag[16];
  #pragma unroll
  for (int kk = 0; kk < 16; ++kk) {
    const float4* src = (const float4*)(Whh + (size_t)Grow * 512 + kk * 32 + kb);
    float4 w0 = src[0], w1 = src[1];
    bf16x8 tt = { (__bf16)w0.x, (__bf16)w0.y, (__bf16)w0.z, (__bf16)w0.w,
                  (__bf16)w1.x, (__bf16)w1.y, (__bf16)w1.z, (__bf16)w1.w };
    bfrag[kk] = tt;
  }

  float c_reg[4] = {0.f, 0.f, 0.f, 0.f};
  f32x4 xq;                                // xp[s][B0+r][Grow], prefetched
  #pragma unroll
  for (int r = 0; r < 4; ++r) xq[r] = xp[(size_t)(B0 + r) * G4 + Grow];

  for (int s = 0; s < S_LEN; ++s) {
    // A-frags: h_s[batch=nl][k], 16B loads (first-touch; L3-resident slab)
    const __bf16* hrow = hs_full + (size_t)s * 8192 + nl * 512 + kb;
    bf16x8 afrag[16];
    #pragma unroll
    for (int kk = 0; kk < 16; ++kk)
      afrag[kk] = *(const bf16x8*)(hrow + kk * 32);

    f32x4 acc0 = xq;                       // C-in = input projection (incl. biases)
    f32x4 acc1 = {0.f, 0.f, 0.f, 0.f};
    #pragma unroll
    for (int kk = 0; kk < 16; kk += 2) {
      acc0 = __builtin_amdgcn_mfma_f32_16x16x32_bf16(afrag[kk],     bfrag[kk],     acc0, 0, 0, 0);
      acc1 = __builtin_amdgcn_mfma_f32_16x16x32_bf16(afrag[kk + 1], bfrag[kk + 1], acc1, 0, 0, 0);
    }

    // prefetch next step's xp while MFMA drains
    if (s + 1 < S_LEN) {
      const float* nx = xp + ((size_t)(s + 1) * BATCH + B0) * G4 + Grow;
      #pragma unroll
      for (int r = 0; r < 4; ++r) xq[r] = nx[(size_t)r * G4];
    }

    f32x4 gates;
    #pragma unroll
    for (int r = 0; r < 4; ++r) gates[r] = acc0[r] + acc1[r];

    // redistribute: this lane takes i,f,g,o of cell c0+(lane&3), batches B0..B0+3
    const int lbase = (lane & 48) | (lane & 3);
    __bf16* dstbase = hs_full + (size_t)(s + 1) * 8192 + (size_t)B0 * 512 + c0 + (lane & 3);
    #pragma unroll
    for (int r = 0; r < 4; ++r) {
      float ig = __shfl(gates[r], lbase + 0);
      float fg = __shfl(gates[r], lbase + 4);
      float gg = __shfl(gates[r], lbase + 8);
      float og = __shfl(gates[r], lbase + 12);
      float si = 1.f / (1.f + __expf(-ig));
      float sf = 1.f / (1.f + __expf(-fg));
      float so = 1.f / (1.f + __expf(-og));
      float ag = fabsf(gg), eg = __expf(-2.f * ag);
      float tg = __builtin_copysignf((1.f - eg) / (1.f + eg), gg);
      float c  = sf * c_reg[r] + si * tg;
      c_reg[r] = c;
      float ac = fabsf(c), ec = __expf(-2.f * ac);
      float tc = __builtin_copysignf((1.f - ec) / (1.f + ec), c);
      float h  = so * tc;
      if ((lane & 12) == 0)                // 16 writer lanes: store as soon as computed
        store_short_sc(dstbase + (size_t)r * 512, (__bf16)h);
    }

    __syncthreads();                       // every wave drains its sc1 stores (vmcnt 0)
    if (tid == 0) {
      __hip_atomic_fetch_add(cnt, 1, __ATOMIC_RELAXED, __HIP_MEMORY_SCOPE_AGENT);
      const int target = NWG_LSTM * (s + 1);
      while (load_cnt_sc(cnt) < target) {}
      if (blockIdx.x == 0)                 // fire-and-forget mirror for consumers
        store_int_sc(mir, s + 1);
    }
    __syncthreads();
  }
}

// ---------------- in-place log_softmax over V=32000 ----------------
__global__ __launch_bounds__(256) void k_logsm(float* __restrict__ out) {
  const int row = blockIdx.x;
  float* p = out + (size_t)row * VOCAB;
  const int tid = threadIdx.x;
  float m = -INFINITY, ssum = 0.f;
  for (int i = tid; i < VOCAB / 4; i += 256) {
    float4 v = ((const float4*)p)[i];
    float nm = fmaxf(fmaxf(m, v.x), fmaxf(fmaxf(v.y, v.z), v.w));
    if (nm > m) { ssum *= __expf(m - nm); m = nm; }
    ssum += __expf(v.x - m) + __expf(v.y - m) + __expf(v.z - m) + __expf(v.w - m);
  }
  #pragma unroll
  for (int off = 32; off > 0; off >>= 1) {
    float mo = __shfl_down(m, off);
    float so = __shfl_down(ssum, off);
    float nm = fmaxf(m, mo);
    ssum = ssum * __expf(m - nm) + so * __expf(mo - nm);
    m = nm;
  }
  __shared__ float sm[4], ss[4], lse_s;
  int wid = tid >> 6;
  if ((tid & 63) == 0) { sm[wid] = m; ss[wid] = ssum; }
  __syncthreads();
  if (tid == 0) {
    float M = sm[0], Ssum = ss[0];
    #pragma unroll
    for (int w = 1; w < 4; ++w) {
      float nm = fmaxf(M, sm[w]);
      Ssum = Ssum * __expf(M - nm) + ss[w] * __expf(sm[w] - nm);
      M = nm;
    }
    lse_s = M + logf(Ssum);
  }
  __syncthreads();
  const float lse = lse_s;
  for (int i = tid; i < VOCAB / 4; i += 256) {
    float4 v = ((const float4*)p)[i];
    v.x -= lse; v.y -= lse; v.z -= lse; v.w -= lse;
    ((float4*)p)[i] = v;
  }
}

extern "C" void kernel_launch(void* const* d_in, const int* in_sizes, int n_in,
                              void* d_out, int out_size, void* d_ws, size_t ws_size,
                              hipStream_t stream) {
  const int*   tok   = (const int*)d_in[0];
  // d_in[1] = input_lengths: unused by the reference
  const float* embed = (const float*)d_in[2];
  const float* W_ih  = (const float*)d_in[3];
  const float* W_hh  = (const float*)d_in[4];
  const float* b_ih  = (const float*)d_in[5];
  const float* b_hh  = (const float*)d_in[6];
  const float* W_lin = (const float*)d_in[7];
  const float* b_lin = (const float*)d_in[8];
  float* out = (float*)d_out;
  char*  ws  = (char*)d_ws;

  int*    cnt      = (int*)(ws + OFF_CNT);
  int*    mir      = (int*)(ws + OFF_MIR);
  float*  bias_sum = (float*)(ws + OFF_BIAS);
  __bf16* xb       = (__bf16*)(ws + OFF_X);
  __bf16* wihb     = (__bf16*)(ws + OFF_WIH);
  __bf16* wlinb    = (__bf16*)(ws + OFF_WLIN);
  float*  xp       = (float*)(ws + OFF_XP);
  __bf16* hs_full  = (__bf16*)(ws + OFF_HS);

  // zero barrier counter + mirror + h_0 slab (required every replay)
  hipMemsetAsync(ws + OFF_CNT, 0, 4096, stream);
  hipMemsetAsync(ws + OFF_HS, 0, BATCH * HDIM * sizeof(__bf16), stream);

  k_prep<<<5128, 256, 0, stream>>>(tok, embed, xb, W_ih, wihb, W_lin, wlinb,
                                   b_ih, b_hh, bias_sum);
  k_gemm2<<<dim3(G4 / 128, M_ROWS / 128), 256, 0, stream>>>(xb, wihb, xp, bias_sum, G4, EDIM);
  k_lstm_fused<<<NWG_LSTM + NTILE_M * NTILE_N, 256, 0, stream>>>(
      xp, W_hh, hs_full, cnt, mir, wlinb, out, b_lin);
  k_logsm<<<4096, 256, 0, stream>>>(out);
}